// Round 13
// baseline (1299.816 us; speedup 1.0000x reference)
//
#include <hip/hip_runtime.h>

// Problem dims
#define Bdim 64
#define Sdim 512
#define Vdim 30000
#define Edim 300
#define Hdim 256
#define Cdim 32
#define G4   1024     // 4*H
#define NROW 32768    // B*S
#define KQ   32       // 256 k-values / 8 per 16B chunk
#define USTAGE 9      // kq-blocks of U staged in DYNAMIC LDS (144 KB)
#define RKQ    12     // kq-blocks of U in VGPRs. FINAL (r11 closed the door:
                      // 64-VGPR cap is unconditional for the lstm shape).
#define EPAIR  (Edim / 2)   // 150 f16-pairs along E
#define KCH    5            // xproj K-chunks of 32 pairs (150 -> 5*32, zero-pad)

// ---------- f16 helpers (store as plain ushort to avoid ABI surprises) -----
typedef _Float16 half2v __attribute__((ext_vector_type(2)));
typedef _Float16 f16x8  __attribute__((ext_vector_type(8)));
typedef float    f32x4  __attribute__((ext_vector_type(4)));
typedef unsigned int u32x4 __attribute__((ext_vector_type(4)));

__device__ __forceinline__ unsigned short f2h_bits(float f) {
    union { _Float16 h; unsigned short u; } v; v.h = (_Float16)f; return v.u;
}
__device__ __forceinline__ float h2f(unsigned short u) {
    union { _Float16 h; unsigned short u; } v; v.u = u; return (float)v.h;
}
__device__ __forceinline__ unsigned int pack2h(float lo, float hi) {
    return (unsigned int)f2h_bits(lo) | ((unsigned int)f2h_bits(hi) << 16);
}
__device__ __forceinline__ float sigf(float x) { return 1.0f / (1.0f + __expf(-x)); }
__device__ __forceinline__ float tanhfast(float x) { return 2.0f / (1.0f + __expf(-2.0f * x)) - 1.0f; }

// 2 MACs from packed f16 pairs, f32 accumulate (v_dot2_f32_f16 when available)
__device__ __forceinline__ float dot2(unsigned int u, unsigned int h, float acc) {
#if __has_builtin(__builtin_amdgcn_fdot2)
    union { unsigned int i; half2v h; } a, b; a.i = u; b.i = h;
    return __builtin_amdgcn_fdot2(a.h, b.h, acc, false);
#else
    acc = fmaf(h2f((unsigned short)(u & 0xffffu)), h2f((unsigned short)(h & 0xffffu)), acc);
    return fmaf(h2f((unsigned short)(u >> 16)), h2f((unsigned short)(h >> 16)), acc);
#endif
}
// 8 MACs from one 16B U chunk and one 16B h chunk (two independent chains)
__device__ __forceinline__ void dot8(float& a0, float& a1, u32x4 uv, u32x4 hv) {
    a0 = dot2(uv.x, hv.x, a0);
    a1 = dot2(uv.y, hv.y, a1);
    a0 = dot2(uv.z, hv.z, a0);
    a1 = dot2(uv.w, hv.w, a1);
}

// ---------- K0a: pack U (f32 [256][1024]) -> f16 chunks [2][32][1024][8] ----
__global__ __launch_bounds__(256) void k_pack_u8(
    const float* __restrict__ Uf, const float* __restrict__ Ub,
    unsigned short* __restrict__ upk8)
{
    int idx = blockIdx.x * 256 + threadIdx.x;   // 0 .. 65535
    if (idx >= 2 * KQ * 1024) return;
    int dir = idx >> 15;
    int rem = idx & 32767;
    int kq  = rem >> 10;
    int n   = rem & 1023;
    const float* U = dir ? Ub : Uf;
    unsigned int w[4];
    #pragma unroll
    for (int p = 0; p < 4; ++p)
        w[p] = pack2h(U[(8 * kq + 2 * p) * G4 + n], U[(8 * kq + 2 * p + 1) * G4 + n]);
    uint4 o = make_uint4(w[0], w[1], w[2], w[3]);
    *(uint4*)&upk8[(size_t)idx * 8] = o;
}

// ---------- K0b: pack emb f32 [V][300] -> f16 pairs [V*150] uints -----------
__global__ __launch_bounds__(256) void k_pack_emb(
    const float* __restrict__ emb, unsigned int* __restrict__ embp)
{
    int p = blockIdx.x * 256 + threadIdx.x;     // flat pair index
    if (p >= Vdim * EPAIR) return;
    float2 v = *(const float2*)&emb[(size_t)2 * p];
    embp[p] = pack2h(v.x, v.y);
}

// ---------- K0c: pack W f32 [300][1024] -> f16 k-pairs [2][150][1024] -------
__global__ __launch_bounds__(256) void k_pack_w(
    const float* __restrict__ Wf, const float* __restrict__ Wb,
    unsigned int* __restrict__ Wp)
{
    int idx = blockIdx.x * 256 + threadIdx.x;   // 0 .. 2*150*1024-1
    if (idx >= 2 * EPAIR * 1024) return;
    int dir = idx / (EPAIR * 1024);
    int rem = idx - dir * (EPAIR * 1024);
    int kp  = rem >> 10;
    int n   = rem & 1023;
    const float* W = dir ? Wb : Wf;
    Wp[idx] = pack2h(W[(2 * kp) * G4 + n], W[(2 * kp + 1) * G4 + n]);
}

// ---------- K0d: pack Wd f32 [512][32] -> f16 k-pairs [256][32] uints -------
__global__ __launch_bounds__(256) void k_pack_wd(
    const float* __restrict__ Wd, unsigned int* __restrict__ WdP)
{
    int i = blockIdx.x * 256 + threadIdx.x;     // kp*32 + c
    if (i >= 256 * 32) return;
    int kp = i >> 5, c = i & 31;
    WdP[i] = pack2h(Wd[(2 * kp) * 32 + c], Wd[(2 * kp + 1) * 32 + c]);
}

// ---------- K1: xproj via MFMA, BOTH dirs per block -------------------------
// grid (512, 8): M-tile 64, N-tile 128, dirs merged. A (token gather) staged
// ONCE, consumed by both dirs' B tiles -> A-gather L2 traffic halves.
// block 256 = 4 waves (2x2). K chunked 5x64 (zero-pad 300->320). +8 f16 row
// pad (144B stride, aligned b128, 2-way banks free). launch_bounds(256,2)
// gives a 256-VGPR budget for the doubled accumulator (64 f32).
__global__ __launch_bounds__(256, 2) void k_xproj(
    const int* __restrict__ tokens, const unsigned int* __restrict__ embp,
    const unsigned int* __restrict__ Wp,
    const float* __restrict__ bf_, const float* __restrict__ bb_,
    unsigned short* __restrict__ xp)
{
    __shared__ unsigned short As[64][72];      // [m][k]  9.2 KB
    __shared__ unsigned short Bs[2][128][72];  // [d][n][k] 36.9 KB
    __shared__ int tokL[64];

    const int m0  = blockIdx.x * 64;
    const int n0  = blockIdx.y * 128;
    const int tid = threadIdx.x;

    if (tid < 64) tokL[tid] = tokens[m0 + tid];
    __syncthreads();

    const int w    = tid >> 6;          // wave 0..3
    const int wm   = w >> 1;            // 0..1 (m-half, 32 rows)
    const int wn   = w & 1;             // 0..1 (n-half, 64 cols)
    const int lane = tid & 63;
    const int lr   = lane & 15;
    const int lh   = lane >> 4;         // 0..3

    f32x4 acc[2][2][4] = {};            // [dir][mt][nt]

    float bv[2][4];
    #pragma unroll
    for (int nt = 0; nt < 4; ++nt) {
        bv[0][nt] = bf_[n0 + wn * 64 + nt * 16 + lr];
        bv[1][nt] = bb_[n0 + wn * 64 + nt * 16 + lr];
    }

    for (int kc = 0; kc < KCH; ++kc) {
        const int k0p = kc * 32;        // base k-pair of this chunk
        if (kc) __syncthreads();        // prior compute done before restage

        // stage A: 64 rows x 32 pairs. thread: row=tid>>2, 8 pairs.
        {
            const int r  = tid >> 2;
            const int jb = (tid & 3) * 8;
            const int tok = tokL[r];
            unsigned int* dst = (unsigned int*)&As[r][0];
            #pragma unroll
            for (int q = 0; q < 8; ++q) {
                int gp = k0p + jb + q;
                dst[jb + q] = (gp < EPAIR) ? embp[(size_t)tok * EPAIR + gp] : 0u;
            }
        }
        // stage B (transposed) for BOTH dirs: 128 cols x 32 pairs each.
        #pragma unroll
        for (int d = 0; d < 2; ++d) {
            const unsigned int* W = Wp + (size_t)d * EPAIR * 1024;
            #pragma unroll
            for (int q = 0; q < 16; ++q) {
                int ii = q * 256 + tid;
                int jp = ii >> 7;           // 0..31
                int c  = ii & 127;
                int gp = k0p + jp;
                unsigned int v = (gp < EPAIR) ? W[(size_t)gp * 1024 + n0 + c] : 0u;
                ((unsigned int*)&Bs[d][c][0])[jp] = v;
            }
        }
        __syncthreads();

        // fragments + MFMA (A frags shared across dirs)
        f16x8 a[2][2];
        #pragma unroll
        for (int mt = 0; mt < 2; ++mt)
            #pragma unroll
            for (int ks = 0; ks < 2; ++ks)
                a[mt][ks] = *(const f16x8*)&As[wm * 32 + mt * 16 + lr][ks * 32 + lh * 8];
        #pragma unroll
        for (int d = 0; d < 2; ++d) {
            #pragma unroll
            for (int nt = 0; nt < 4; ++nt) {
                f16x8 b0 = *(const f16x8*)&Bs[d][wn * 64 + nt * 16 + lr][lh * 8];
                f16x8 b1 = *(const f16x8*)&Bs[d][wn * 64 + nt * 16 + lr][32 + lh * 8];
                #pragma unroll
                for (int mt = 0; mt < 2; ++mt) {
                    acc[d][mt][nt] = __builtin_amdgcn_mfma_f32_16x16x32_f16(a[mt][0], b0, acc[d][mt][nt], 0, 0, 0);
                    acc[d][mt][nt] = __builtin_amdgcn_mfma_f32_16x16x32_f16(a[mt][1], b1, acc[d][mt][nt], 0, 0, 0);
                }
            }
        }
    }

    // epilogue: D lane mapping col=lane&15, row=(lane>>4)*4+reg
    #pragma unroll
    for (int d = 0; d < 2; ++d) {
        size_t base = (size_t)d * NROW * G4;
        #pragma unroll
        for (int mt = 0; mt < 2; ++mt) {
            #pragma unroll
            for (int nt = 0; nt < 4; ++nt) {
                int col = n0 + wn * 64 + nt * 16 + lr;
                #pragma unroll
                for (int rr = 0; rr < 4; ++rr) {
                    int row = m0 + wm * 32 + mt * 16 + lh * 4 + rr;
                    xp[base + (size_t)row * G4 + col] = f2h_bits(acc[d][mt][nt][rr] + bv[d][nt]);
                }
            }
        }
    }
}

// ---------- K2: LSTM recurrence (r5/r10-proven form, FINAL) -----------------
// 128 WGs = (dir, batch), 1024 threads (16 waves/CU). Thread n owns column n.
// U kq-blocks: [0,9) in 144KB DYNAMIC LDS, [9,21) in VGPRs (RKQ=12),
// remaining 11 streamed from L2 (176 KB/step). Serial n<256 tail.
__global__ __launch_bounds__(1024) void k_lstm(
    const unsigned short* __restrict__ upk8,   // [2][KQ][1024][8] f16
    const unsigned short* __restrict__ xp,     // [2][NROW][1024]  f16
    unsigned short* __restrict__ hout)         // [NROW][512] f16 = [hf|hb]
{
    const int bx  = blockIdx.x;
    const int dir = bx >> 6;
    const int b   = bx & 63;
    const int n   = threadIdx.x;               // 0..1023
    const int gi  = n >> 8;                    // gate: 0=i 1=f 2=g 3=o
    const unsigned short* __restrict__ Uq = upk8 + (size_t)dir * (KQ * 1024 * 8);
    const unsigned short* __restrict__ xpd =
        xp + (size_t)dir * NROW * G4 + (size_t)b * Sdim * G4;

    __shared__ float          abuf[1024];                   // 4 KB gates
    __shared__ __align__(16) unsigned short hl[256];        // f16 h
    extern __shared__ __align__(16) unsigned short ust[];   // 144 KB (kq 0..8)

    {   // vectorized one-time LDS stage of U kq-blocks [0,USTAGE)
        const u32x4* src = (const u32x4*)Uq;
        u32x4*       dst = (u32x4*)ust;
        for (int i = n; i < USTAGE * 1024; i += 1024) dst[i] = src[i];
    }
    // register-stage U kq-blocks [USTAGE, USTAGE+RKQ) — step-invariant
    u32x4 ur[RKQ];
    #pragma unroll
    for (int r = 0; r < RKQ; ++r)
        ur[r] = *(const u32x4*)&Uq[((size_t)(USTAGE + r) * 1024 + n) * 8];

    if (n < 256) hl[n] = 0;
    float c = 0.0f;
    __syncthreads();

    for (int step = 0; step < Sdim; ++step) {
        const int t = dir ? (Sdim - 1 - step) : step;
        float zx = h2f(xpd[(size_t)t * G4 + n]);   // issued early, used late
        float a0 = 0.0f, a1 = 0.0f;
        // streamed-from-L2 blocks (issue loads first; compiler pipelines)
        #pragma unroll
        for (int kq = USTAGE + RKQ; kq < KQ; ++kq) {
            u32x4 uv = *(const u32x4*)&Uq[((size_t)kq * 1024 + n) * 8];
            u32x4 hv = *(const u32x4*)&hl[kq * 8];
            dot8(a0, a1, uv, hv);
        }
        // register-staged blocks
        #pragma unroll
        for (int r = 0; r < RKQ; ++r) {
            u32x4 hv = *(const u32x4*)&hl[(USTAGE + r) * 8];
            dot8(a0, a1, ur[r], hv);
        }
        // LDS-staged blocks
        #pragma unroll
        for (int kq = 0; kq < USTAGE; ++kq) {
            u32x4 uv = *(const u32x4*)&ust[(kq * 1024 + n) * 8];
            u32x4 hv = *(const u32x4*)&hl[kq * 8];
            dot8(a0, a1, uv, hv);
        }
        float z = zx + a0 + a1;
        float a = (gi == 2) ? tanhfast(z) : sigf(z);
        abuf[n] = a;
        __syncthreads();               // abuf complete; all hl readers done
        if (n < 256) {
            float iv = abuf[n];
            float fv = abuf[n + 256];
            float gv = abuf[n + 512];
            float ov = abuf[n + 768];
            c = fv * c + iv * gv;
            float hn = ov * tanhfast(c);
            unsigned short hb = f2h_bits(hn);
            hl[n] = hb;
            hout[((size_t)(b * Sdim + t)) * 512 + dir * 256 + n] = hb;
        }
        __syncthreads();               // hl ready for next step
    }
}

// ---------- K3: logits = [hf|hb] @ Wd + bd via MFMA (r12-proven) ------------
__global__ __launch_bounds__(256, 4) void k_dense(
    const unsigned short* __restrict__ hall, const unsigned int* __restrict__ WdP,
    const float* __restrict__ bd, float* __restrict__ outL)
{
    __shared__ unsigned int wlT[32 * 260];   // 33.3 KB, [c][kp]
    const int r0  = blockIdx.x * 64;
    const int tid = threadIdx.x;

    for (int i = tid; i < 256 * 32; i += 256) {
        int kp = i >> 5, c = i & 31;
        wlT[c * 260 + kp] = WdP[i];
    }
    __syncthreads();

    const int w    = tid >> 6;          // wave 0..3 -> rows r0 + w*16 ..
    const int lane = tid & 63;
    const int lr   = lane & 15;
    const int lh   = lane >> 4;         // 0..3

    const unsigned short* arow = hall + (size_t)(r0 + w * 16 + lr) * 512;
    f32x4 acc[2] = {};                  // 2 n-tiles of 16 cols

    #pragma unroll
    for (int kc = 0; kc < 16; ++kc) {   // K = 512 = 16 x 32
        f16x8 av = *(const f16x8*)&arow[kc * 32 + lh * 8];
        f16x8 b0 = *(const f16x8*)((const unsigned int*)wlT + lr * 260 + kc * 16 + lh * 4);
        f16x8 b1 = *(const f16x8*)((const unsigned int*)wlT + (16 + lr) * 260 + kc * 16 + lh * 4);
        acc[0] = __builtin_amdgcn_mfma_f32_16x16x32_f16(av, b0, acc[0], 0, 0, 0);
        acc[1] = __builtin_amdgcn_mfma_f32_16x16x32_f16(av, b1, acc[1], 0, 0, 0);
    }

    // D mapping: col = nt*16 + lr, row = r0 + w*16 + lh*4 + rr
    #pragma unroll
    for (int nt = 0; nt < 2; ++nt) {
        int col = nt * 16 + lr;
        float bdv = bd[col];
        #pragma unroll
        for (int rr = 0; rr < 4; ++rr) {
            int row = r0 + w * 16 + lh * 4 + rr;
            outL[(size_t)row * 32 + col] = acc[nt][rr] + bdv;
        }
    }
}

// ---------- K4: CRF log-likelihood, single-wave LDS-alpha (r11-proven) ------
// grid 64, block 64 (ONE wave). alpha in LDS: the per-iter gather compiles to
// 4x ds_read_b128 (the r12 shfl form forced 16 serial ds_bpermute — reverted).
__global__ __launch_bounds__(64) void k_crf(
    const float* __restrict__ logits, const int* __restrict__ targets,
    const int* __restrict__ lengths, const float* __restrict__ trans,
    float* __restrict__ out_ll, float* __restrict__ out_trans)
{
    const int b    = blockIdx.x;
    const int lane = threadIdx.x;          // 0..63
    __shared__ __align__(16) float alpha[32];

    if (b == 0)
        for (int i = lane; i < 1024; i += 64) out_trans[i] = trans[i];

    const int len = lengths[b];
    const float* lg = logits + (size_t)b * Sdim * Cdim;
    const int*   tg = targets + b * Sdim;

    float ub = 0.0f;
    for (int t = lane; t < Sdim; t += 64) {
        if (t < len) {
            ub += lg[t * 32 + tg[t]];
            if (t >= 1) ub += trans[tg[t - 1] * 32 + tg[t]];
        }
    }
    #pragma unroll
    for (int m = 32; m >= 1; m >>= 1) ub += __shfl_xor(ub, m);

    const int j = lane & 31, half = lane >> 5;
    float trow16[16];
    #pragma unroll
    for (int q = 0; q < 16; ++q) trow16[q] = trans[(half * 16 + q) * 32 + j];

    if (lane < 32) alpha[lane] = lg[lane];
    __syncthreads();

    float lcur = (len > 1) ? lg[32 + j] : 0.0f;
    for (int t = 1; t < len; ++t) {
        float lnxt = (t + 1 < len) ? lg[(t + 1) * 32 + j] : 0.0f;   // prefetch
        float v[16];
        #pragma unroll
        for (int q = 0; q < 16; ++q) v[q] = alpha[half * 16 + q] + trow16[q];
        float m0 = v[0], m1 = v[1], m2 = v[2], m3 = v[3];
        #pragma unroll
        for (int q = 4; q < 16; q += 4) {
            m0 = fmaxf(m0, v[q]);
            m1 = fmaxf(m1, v[q + 1]);
            m2 = fmaxf(m2, v[q + 2]);
            m3 = fmaxf(m3, v[q + 3]);
        }
        float ml = fmaxf(fmaxf(m0, m1), fmaxf(m2, m3));
        float m  = fmaxf(ml, __shfl_xor(ml, 32));
        float s0 = 0.0f, s1 = 0.0f, s2 = 0.0f, s3 = 0.0f;
        #pragma unroll
        for (int q = 0; q < 16; q += 4) {
            s0 += __expf(v[q] - m);
            s1 += __expf(v[q + 1] - m);
            s2 += __expf(v[q + 2] - m);
            s3 += __expf(v[q + 3] - m);
        }
        float sl = (s0 + s1) + (s2 + s3);
        float s  = sl + __shfl_xor(sl, 32);
        float nv = m + __logf(s) + lcur;
        __syncthreads();
        if (lane < 32) alpha[lane] = nv;
        __syncthreads();
        lcur = lnxt;
    }
    if (lane == 0) {
        float m = -3.0e38f;
        for (int q = 0; q < 32; ++q) m = fmaxf(m, alpha[q]);
        float s = 0.0f;
        for (int q = 0; q < 32; ++q) s += __expf(alpha[q] - m);
        out_ll[b] = ub - (m + __logf(s));
    }
}

// ---------------------------------------------------------------------------
extern "C" void kernel_launch(void* const* d_in, const int* in_sizes, int n_in,
                              void* d_out, int out_size, void* d_ws, size_t ws_size,
                              hipStream_t stream) {
    (void)in_sizes; (void)n_in; (void)out_size; (void)ws_size;
    const int*   tokens  = (const int*)d_in[0];
    const int*   lengths = (const int*)d_in[1];
    const int*   targets = (const int*)d_in[2];
    const float* emb     = (const float*)d_in[3];
    const float* Wf      = (const float*)d_in[4];
    const float* Uf      = (const float*)d_in[5];
    const float* bf_     = (const float*)d_in[6];
    const float* Wb      = (const float*)d_in[7];
    const float* Ub      = (const float*)d_in[8];
    const float* bb_     = (const float*)d_in[9];
    const float* Wd      = (const float*)d_in[10];
    const float* bd      = (const float*)d_in[11];
    const float* trans   = (const float*)d_in[12];

    float* out_logits = (float*)d_out;                 // 1048576
    float* out_ll     = out_logits + 1048576;          // 64
    float* out_trans  = out_ll + 64;                   // 1024

    // ws layout (~161 MiB, unchanged):
    //   [0, 1MB)              ushort upk8[2][32][1024][8]   (f16 U chunks)
    //   [1MB, 1MB+128MB)      ushort xp [2][NROW][1024]     (f16)
    //   [.., +32MB)           ushort hall[NROW][512]        (f16)
    // embp (18MB) + Wp (1.2MB) live INSIDE the hall region (dead after xproj).
    // WdP (32KB) reuses the upk8 region (dead after k_lstm).
    char* ws = (char*)d_ws;
    unsigned short* upk8 = (unsigned short*)ws;
    unsigned short* xp   = (unsigned short*)(ws + (1u << 20));
    char*           hreg = ws + (1u << 20) + (size_t)2 * NROW * G4 * 2;
    unsigned short* hall = (unsigned short*)hreg;
    unsigned int*   embp = (unsigned int*)hreg;                       // 18.0 MB
    unsigned int*   Wp   = (unsigned int*)(hreg + (size_t)Vdim * EPAIR * 4); // 1.2 MB
    unsigned int*   WdP  = (unsigned int*)ws;                         // after lstm

    const size_t lstm_dyn_lds = (size_t)USTAGE * 1024 * 8 * 2;        // 147456 B

    k_pack_u8 <<<dim3(256), dim3(256), 0, stream>>>(Uf, Ub, upk8);
    k_pack_emb<<<dim3((Vdim * EPAIR + 255) / 256), dim3(256), 0, stream>>>(emb, embp);
    k_pack_w  <<<dim3((2 * EPAIR * 1024 + 255) / 256), dim3(256), 0, stream>>>(Wf, Wb, Wp);
    k_xproj   <<<dim3(NROW / 64, 8), dim3(256), 0, stream>>>(tokens, embp, Wp, bf_, bb_, xp);
    k_lstm    <<<dim3(128), dim3(1024), lstm_dyn_lds, stream>>>(upk8, xp, hall);
    k_pack_wd <<<dim3(32), dim3(256), 0, stream>>>(Wd, WdP);
    k_dense   <<<dim3(NROW / 64), dim3(256), 0, stream>>>(hall, WdP, bd, out_logits);
    k_crf     <<<dim3(64), dim3(64), 0, stream>>>(out_logits, targets, lengths, trans, out_ll, out_trans);
}

// Round 14
// 1159.431 us; speedup vs baseline: 1.1211x; 1.1211x over previous
//
#include <hip/hip_runtime.h>

// Problem dims
#define Bdim 64
#define Sdim 512
#define Vdim 30000
#define Edim 300
#define Hdim 256
#define Cdim 32
#define G4   1024     // 4*H
#define NROW 32768    // B*S
#define KQ   32       // 256 k-values / 8 per 16B chunk
#define USTAGE 9      // kq-blocks of U staged in DYNAMIC LDS (144 KB)
#define RKQ    12     // kq-blocks of U in VGPRs. FINAL (r11 closed the door:
                      // 64-VGPR cap is unconditional for the lstm shape).
#define EPAIR  (Edim / 2)   // 150 f16-pairs along E
#define KCH    5            // xproj K-chunks of 32 pairs (150 -> 5*32, zero-pad)

// ---------- f16 helpers (store as plain ushort to avoid ABI surprises) -----
typedef _Float16 half2v __attribute__((ext_vector_type(2)));
typedef _Float16 f16x8  __attribute__((ext_vector_type(8)));
typedef float    f32x4  __attribute__((ext_vector_type(4)));
typedef unsigned int u32x4 __attribute__((ext_vector_type(4)));

__device__ __forceinline__ unsigned short f2h_bits(float f) {
    union { _Float16 h; unsigned short u; } v; v.h = (_Float16)f; return v.u;
}
__device__ __forceinline__ float h2f(unsigned short u) {
    union { _Float16 h; unsigned short u; } v; v.u = u; return (float)v.h;
}
__device__ __forceinline__ unsigned int pack2h(float lo, float hi) {
    return (unsigned int)f2h_bits(lo) | ((unsigned int)f2h_bits(hi) << 16);
}
__device__ __forceinline__ float sigf(float x) { return 1.0f / (1.0f + __expf(-x)); }
__device__ __forceinline__ float tanhfast(float x) { return 2.0f / (1.0f + __expf(-2.0f * x)) - 1.0f; }

// 2 MACs from packed f16 pairs, f32 accumulate (v_dot2_f32_f16 when available)
__device__ __forceinline__ float dot2(unsigned int u, unsigned int h, float acc) {
#if __has_builtin(__builtin_amdgcn_fdot2)
    union { unsigned int i; half2v h; } a, b; a.i = u; b.i = h;
    return __builtin_amdgcn_fdot2(a.h, b.h, acc, false);
#else
    acc = fmaf(h2f((unsigned short)(u & 0xffffu)), h2f((unsigned short)(h & 0xffffu)), acc);
    return fmaf(h2f((unsigned short)(u >> 16)), h2f((unsigned short)(h >> 16)), acc);
#endif
}
// 8 MACs from one 16B U chunk and one 16B h chunk (two independent chains)
__device__ __forceinline__ void dot8(float& a0, float& a1, u32x4 uv, u32x4 hv) {
    a0 = dot2(uv.x, hv.x, a0);
    a1 = dot2(uv.y, hv.y, a1);
    a0 = dot2(uv.z, hv.z, a0);
    a1 = dot2(uv.w, hv.w, a1);
}

// ---------- K0a: pack U (f32 [256][1024]) -> f16 chunks [2][32][1024][8] ----
__global__ __launch_bounds__(256) void k_pack_u8(
    const float* __restrict__ Uf, const float* __restrict__ Ub,
    unsigned short* __restrict__ upk8)
{
    int idx = blockIdx.x * 256 + threadIdx.x;   // 0 .. 65535
    if (idx >= 2 * KQ * 1024) return;
    int dir = idx >> 15;
    int rem = idx & 32767;
    int kq  = rem >> 10;
    int n   = rem & 1023;
    const float* U = dir ? Ub : Uf;
    unsigned int w[4];
    #pragma unroll
    for (int p = 0; p < 4; ++p)
        w[p] = pack2h(U[(8 * kq + 2 * p) * G4 + n], U[(8 * kq + 2 * p + 1) * G4 + n]);
    uint4 o = make_uint4(w[0], w[1], w[2], w[3]);
    *(uint4*)&upk8[(size_t)idx * 8] = o;
}

// ---------- K0b: pack emb f32 [V][300] -> f16 pairs [V*150] uints -----------
__global__ __launch_bounds__(256) void k_pack_emb(
    const float* __restrict__ emb, unsigned int* __restrict__ embp)
{
    int p = blockIdx.x * 256 + threadIdx.x;     // flat pair index
    if (p >= Vdim * EPAIR) return;
    float2 v = *(const float2*)&emb[(size_t)2 * p];
    embp[p] = pack2h(v.x, v.y);
}

// ---------- K0c: pack W f32 [300][1024] -> f16 k-pairs [2][150][1024] -------
__global__ __launch_bounds__(256) void k_pack_w(
    const float* __restrict__ Wf, const float* __restrict__ Wb,
    unsigned int* __restrict__ Wp)
{
    int idx = blockIdx.x * 256 + threadIdx.x;   // 0 .. 2*150*1024-1
    if (idx >= 2 * EPAIR * 1024) return;
    int dir = idx / (EPAIR * 1024);
    int rem = idx - dir * (EPAIR * 1024);
    int kp  = rem >> 10;
    int n   = rem & 1023;
    const float* W = dir ? Wb : Wf;
    Wp[idx] = pack2h(W[(2 * kp) * G4 + n], W[(2 * kp + 1) * G4 + n]);
}

// ---------- K0d: pack Wd f32 [512][32] -> f16 k-pairs [256][32] uints -------
__global__ __launch_bounds__(256) void k_pack_wd(
    const float* __restrict__ Wd, unsigned int* __restrict__ WdP)
{
    int i = blockIdx.x * 256 + threadIdx.x;     // kp*32 + c
    if (i >= 256 * 32) return;
    int kp = i >> 5, c = i & 31;
    WdP[i] = pack2h(Wd[(2 * kp) * 32 + c], Wd[(2 * kp + 1) * 32 + c]);
}

// ---------- K1: xproj via MFMA (r10-proven split-dir form) ------------------
// grid (512, 8, 2): M-tile 64, N-tile 128, per-dir. block 256 = 4 waves (2x2).
// (r13's dir-merge regressed: 4 waves over 2x work + serialized B-staging
//  beats the halved A-gather. Reverted to this form.)
__global__ __launch_bounds__(256, 4) void k_xproj(
    const int* __restrict__ tokens, const unsigned int* __restrict__ embp,
    const unsigned int* __restrict__ Wp,
    const float* __restrict__ bf_, const float* __restrict__ bb_,
    unsigned short* __restrict__ xp)
{
    __shared__ unsigned short As[64][72];   // [m][k]  9.2 KB
    __shared__ unsigned short Bs[128][72];  // [n][k] 18.4 KB
    __shared__ int tokL[64];

    const int m0  = blockIdx.x * 64;
    const int n0  = blockIdx.y * 128;
    const int dir = blockIdx.z;
    const unsigned int* W = Wp + (size_t)dir * EPAIR * 1024;
    const float* bias = dir ? bb_ : bf_;
    const int tid = threadIdx.x;

    if (tid < 64) tokL[tid] = tokens[m0 + tid];
    __syncthreads();

    const int w    = tid >> 6;          // wave 0..3
    const int wm   = w >> 1;            // 0..1 (m-half, 32 rows)
    const int wn   = w & 1;             // 0..1 (n-half, 64 cols)
    const int lane = tid & 63;
    const int lr   = lane & 15;
    const int lh   = lane >> 4;         // 0..3

    f32x4 acc[2][4] = {};               // [mt][nt]

    float bv[4];
    #pragma unroll
    for (int nt = 0; nt < 4; ++nt)
        bv[nt] = bias[n0 + wn * 64 + nt * 16 + lr];

    for (int kc = 0; kc < KCH; ++kc) {
        const int k0p = kc * 32;        // base k-pair of this chunk
        if (kc) __syncthreads();        // prior compute done before restage

        // stage A: 64 rows x 32 pairs. thread: row=tid>>2, 8 pairs.
        {
            const int r  = tid >> 2;
            const int jb = (tid & 3) * 8;
            const int tok = tokL[r];
            unsigned int* dst = (unsigned int*)&As[r][0];
            #pragma unroll
            for (int q = 0; q < 8; ++q) {
                int gp = k0p + jb + q;
                dst[jb + q] = (gp < EPAIR) ? embp[(size_t)tok * EPAIR + gp] : 0u;
            }
        }
        // stage B (transposed): 128 cols x 32 pairs.
        {
            #pragma unroll
            for (int q = 0; q < 16; ++q) {
                int ii = q * 256 + tid;
                int jp = ii >> 7;           // 0..31
                int c  = ii & 127;
                int gp = k0p + jp;
                unsigned int v = (gp < EPAIR) ? W[(size_t)gp * 1024 + n0 + c] : 0u;
                ((unsigned int*)&Bs[c][0])[jp] = v;
            }
        }
        __syncthreads();

        // fragments + MFMA
        f16x8 a[2][2];
        #pragma unroll
        for (int mt = 0; mt < 2; ++mt)
            #pragma unroll
            for (int ks = 0; ks < 2; ++ks)
                a[mt][ks] = *(const f16x8*)&As[wm * 32 + mt * 16 + lr][ks * 32 + lh * 8];
        #pragma unroll
        for (int nt = 0; nt < 4; ++nt) {
            f16x8 b0 = *(const f16x8*)&Bs[wn * 64 + nt * 16 + lr][lh * 8];
            f16x8 b1 = *(const f16x8*)&Bs[wn * 64 + nt * 16 + lr][32 + lh * 8];
            #pragma unroll
            for (int mt = 0; mt < 2; ++mt) {
                acc[mt][nt] = __builtin_amdgcn_mfma_f32_16x16x32_f16(a[mt][0], b0, acc[mt][nt], 0, 0, 0);
                acc[mt][nt] = __builtin_amdgcn_mfma_f32_16x16x32_f16(a[mt][1], b1, acc[mt][nt], 0, 0, 0);
            }
        }
    }

    // epilogue: D lane mapping col=lane&15, row=(lane>>4)*4+reg
    size_t base = (size_t)dir * NROW * G4;
    #pragma unroll
    for (int mt = 0; mt < 2; ++mt) {
        #pragma unroll
        for (int nt = 0; nt < 4; ++nt) {
            int col = n0 + wn * 64 + nt * 16 + lr;
            #pragma unroll
            for (int rr = 0; rr < 4; ++rr) {
                int row = m0 + wm * 32 + mt * 16 + lh * 4 + rr;
                xp[base + (size_t)row * G4 + col] = f2h_bits(acc[mt][nt][rr] + bv[nt]);
            }
        }
    }
}

// ---------- K2: LSTM recurrence (r5/r10-proven form, FINAL) -----------------
// 128 WGs = (dir, batch), 1024 threads (16 waves/CU). Thread n owns column n.
// U kq-blocks: [0,9) in 144KB DYNAMIC LDS, [9,21) in VGPRs (RKQ=12),
// remaining 11 streamed from L2 (176 KB/step). Serial n<256 tail.
__global__ __launch_bounds__(1024) void k_lstm(
    const unsigned short* __restrict__ upk8,   // [2][KQ][1024][8] f16
    const unsigned short* __restrict__ xp,     // [2][NROW][1024]  f16
    unsigned short* __restrict__ hout)         // [NROW][512] f16 = [hf|hb]
{
    const int bx  = blockIdx.x;
    const int dir = bx >> 6;
    const int b   = bx & 63;
    const int n   = threadIdx.x;               // 0..1023
    const int gi  = n >> 8;                    // gate: 0=i 1=f 2=g 3=o
    const unsigned short* __restrict__ Uq = upk8 + (size_t)dir * (KQ * 1024 * 8);
    const unsigned short* __restrict__ xpd =
        xp + (size_t)dir * NROW * G4 + (size_t)b * Sdim * G4;

    __shared__ float          abuf[1024];                   // 4 KB gates
    __shared__ __align__(16) unsigned short hl[256];        // f16 h
    extern __shared__ __align__(16) unsigned short ust[];   // 144 KB (kq 0..8)

    {   // vectorized one-time LDS stage of U kq-blocks [0,USTAGE)
        const u32x4* src = (const u32x4*)Uq;
        u32x4*       dst = (u32x4*)ust;
        for (int i = n; i < USTAGE * 1024; i += 1024) dst[i] = src[i];
    }
    // register-stage U kq-blocks [USTAGE, USTAGE+RKQ) — step-invariant
    u32x4 ur[RKQ];
    #pragma unroll
    for (int r = 0; r < RKQ; ++r)
        ur[r] = *(const u32x4*)&Uq[((size_t)(USTAGE + r) * 1024 + n) * 8];

    if (n < 256) hl[n] = 0;
    float c = 0.0f;
    __syncthreads();

    for (int step = 0; step < Sdim; ++step) {
        const int t = dir ? (Sdim - 1 - step) : step;
        float zx = h2f(xpd[(size_t)t * G4 + n]);   // issued early, used late
        float a0 = 0.0f, a1 = 0.0f;
        // streamed-from-L2 blocks (issue loads first; compiler pipelines)
        #pragma unroll
        for (int kq = USTAGE + RKQ; kq < KQ; ++kq) {
            u32x4 uv = *(const u32x4*)&Uq[((size_t)kq * 1024 + n) * 8];
            u32x4 hv = *(const u32x4*)&hl[kq * 8];
            dot8(a0, a1, uv, hv);
        }
        // register-staged blocks
        #pragma unroll
        for (int r = 0; r < RKQ; ++r) {
            u32x4 hv = *(const u32x4*)&hl[(USTAGE + r) * 8];
            dot8(a0, a1, ur[r], hv);
        }
        // LDS-staged blocks
        #pragma unroll
        for (int kq = 0; kq < USTAGE; ++kq) {
            u32x4 uv = *(const u32x4*)&ust[(kq * 1024 + n) * 8];
            u32x4 hv = *(const u32x4*)&hl[kq * 8];
            dot8(a0, a1, uv, hv);
        }
        float z = zx + a0 + a1;
        float a = (gi == 2) ? tanhfast(z) : sigf(z);
        abuf[n] = a;
        __syncthreads();               // abuf complete; all hl readers done
        if (n < 256) {
            float iv = abuf[n];
            float fv = abuf[n + 256];
            float gv = abuf[n + 512];
            float ov = abuf[n + 768];
            c = fv * c + iv * gv;
            float hn = ov * tanhfast(c);
            unsigned short hb = f2h_bits(hn);
            hl[n] = hb;
            hout[((size_t)(b * Sdim + t)) * 512 + dir * 256 + n] = hb;
        }
        __syncthreads();               // hl ready for next step
    }
}

// ---------- K3: logits = [hf|hb] @ Wd + bd via MFMA (r12-proven) ------------
__global__ __launch_bounds__(256, 4) void k_dense(
    const unsigned short* __restrict__ hall, const unsigned int* __restrict__ WdP,
    const float* __restrict__ bd, float* __restrict__ outL)
{
    __shared__ unsigned int wlT[32 * 260];   // 33.3 KB, [c][kp]
    const int r0  = blockIdx.x * 64;
    const int tid = threadIdx.x;

    for (int i = tid; i < 256 * 32; i += 256) {
        int kp = i >> 5, c = i & 31;
        wlT[c * 260 + kp] = WdP[i];
    }
    __syncthreads();

    const int w    = tid >> 6;          // wave 0..3 -> rows r0 + w*16 ..
    const int lane = tid & 63;
    const int lr   = lane & 15;
    const int lh   = lane >> 4;         // 0..3

    const unsigned short* arow = hall + (size_t)(r0 + w * 16 + lr) * 512;
    f32x4 acc[2] = {};                  // 2 n-tiles of 16 cols

    #pragma unroll
    for (int kc = 0; kc < 16; ++kc) {   // K = 512 = 16 x 32
        f16x8 av = *(const f16x8*)&arow[kc * 32 + lh * 8];
        f16x8 b0 = *(const f16x8*)((const unsigned int*)wlT + lr * 260 + kc * 16 + lh * 4);
        f16x8 b1 = *(const f16x8*)((const unsigned int*)wlT + (16 + lr) * 260 + kc * 16 + lh * 4);
        acc[0] = __builtin_amdgcn_mfma_f32_16x16x32_f16(av, b0, acc[0], 0, 0, 0);
        acc[1] = __builtin_amdgcn_mfma_f32_16x16x32_f16(av, b1, acc[1], 0, 0, 0);
    }

    // D mapping: col = nt*16 + lr, row = r0 + w*16 + lh*4 + rr
    #pragma unroll
    for (int nt = 0; nt < 2; ++nt) {
        int col = nt * 16 + lr;
        float bdv = bd[col];
        #pragma unroll
        for (int rr = 0; rr < 4; ++rr) {
            int row = r0 + w * 16 + lh * 4 + rr;
            outL[(size_t)row * 32 + col] = acc[nt][rr] + bdv;
        }
    }
}

// ---------- K4: CRF log-likelihood, single-wave LDS-alpha (r11-proven) ------
// grid 64, block 64 (ONE wave). alpha in LDS: the per-iter gather compiles to
// 4x ds_read_b128 (the r12 shfl form forced 16 serial ds_bpermute — reverted).
__global__ __launch_bounds__(64) void k_crf(
    const float* __restrict__ logits, const int* __restrict__ targets,
    const int* __restrict__ lengths, const float* __restrict__ trans,
    float* __restrict__ out_ll, float* __restrict__ out_trans)
{
    const int b    = blockIdx.x;
    const int lane = threadIdx.x;          // 0..63
    __shared__ __align__(16) float alpha[32];

    if (b == 0)
        for (int i = lane; i < 1024; i += 64) out_trans[i] = trans[i];

    const int len = lengths[b];
    const float* lg = logits + (size_t)b * Sdim * Cdim;
    const int*   tg = targets + b * Sdim;

    float ub = 0.0f;
    for (int t = lane; t < Sdim; t += 64) {
        if (t < len) {
            ub += lg[t * 32 + tg[t]];
            if (t >= 1) ub += trans[tg[t - 1] * 32 + tg[t]];
        }
    }
    #pragma unroll
    for (int m = 32; m >= 1; m >>= 1) ub += __shfl_xor(ub, m);

    const int j = lane & 31, half = lane >> 5;
    float trow16[16];
    #pragma unroll
    for (int q = 0; q < 16; ++q) trow16[q] = trans[(half * 16 + q) * 32 + j];

    if (lane < 32) alpha[lane] = lg[lane];
    __syncthreads();

    float lcur = (len > 1) ? lg[32 + j] : 0.0f;
    for (int t = 1; t < len; ++t) {
        float lnxt = (t + 1 < len) ? lg[(t + 1) * 32 + j] : 0.0f;   // prefetch
        float v[16];
        #pragma unroll
        for (int q = 0; q < 16; ++q) v[q] = alpha[half * 16 + q] + trow16[q];
        float m0 = v[0], m1 = v[1], m2 = v[2], m3 = v[3];
        #pragma unroll
        for (int q = 4; q < 16; q += 4) {
            m0 = fmaxf(m0, v[q]);
            m1 = fmaxf(m1, v[q + 1]);
            m2 = fmaxf(m2, v[q + 2]);
            m3 = fmaxf(m3, v[q + 3]);
        }
        float ml = fmaxf(fmaxf(m0, m1), fmaxf(m2, m3));
        float m  = fmaxf(ml, __shfl_xor(ml, 32));
        float s0 = 0.0f, s1 = 0.0f, s2 = 0.0f, s3 = 0.0f;
        #pragma unroll
        for (int q = 0; q < 16; q += 4) {
            s0 += __expf(v[q] - m);
            s1 += __expf(v[q + 1] - m);
            s2 += __expf(v[q + 2] - m);
            s3 += __expf(v[q + 3] - m);
        }
        float sl = (s0 + s1) + (s2 + s3);
        float s  = sl + __shfl_xor(sl, 32);
        float nv = m + __logf(s) + lcur;
        __syncthreads();
        if (lane < 32) alpha[lane] = nv;
        __syncthreads();
        lcur = lnxt;
    }
    if (lane == 0) {
        float m = -3.0e38f;
        for (int q = 0; q < 32; ++q) m = fmaxf(m, alpha[q]);
        float s = 0.0f;
        for (int q = 0; q < 32; ++q) s += __expf(alpha[q] - m);
        out_ll[b] = ub - (m + __logf(s));
    }
}

// ---------------------------------------------------------------------------
extern "C" void kernel_launch(void* const* d_in, const int* in_sizes, int n_in,
                              void* d_out, int out_size, void* d_ws, size_t ws_size,
                              hipStream_t stream) {
    (void)in_sizes; (void)n_in; (void)out_size; (void)ws_size;
    const int*   tokens  = (const int*)d_in[0];
    const int*   lengths = (const int*)d_in[1];
    const int*   targets = (const int*)d_in[2];
    const float* emb     = (const float*)d_in[3];
    const float* Wf      = (const float*)d_in[4];
    const float* Uf      = (const float*)d_in[5];
    const float* bf_     = (const float*)d_in[6];
    const float* Wb      = (const float*)d_in[7];
    const float* Ub      = (const float*)d_in[8];
    const float* bb_     = (const float*)d_in[9];
    const float* Wd      = (const float*)d_in[10];
    const float* bd      = (const float*)d_in[11];
    const float* trans   = (const float*)d_in[12];

    float* out_logits = (float*)d_out;                 // 1048576
    float* out_ll     = out_logits + 1048576;          // 64
    float* out_trans  = out_ll + 64;                   // 1024

    // ws layout (~161 MiB, unchanged):
    //   [0, 1MB)              ushort upk8[2][32][1024][8]   (f16 U chunks)
    //   [1MB, 1MB+128MB)      ushort xp [2][NROW][1024]     (f16)
    //   [.., +32MB)           ushort hall[NROW][512]        (f16)
    // embp (18MB) + Wp (1.2MB) live INSIDE the hall region (dead after xproj).
    // WdP (32KB) reuses the upk8 region (dead after k_lstm).
    char* ws = (char*)d_ws;
    unsigned short* upk8 = (unsigned short*)ws;
    unsigned short* xp   = (unsigned short*)(ws + (1u << 20));
    char*           hreg = ws + (1u << 20) + (size_t)2 * NROW * G4 * 2;
    unsigned short* hall = (unsigned short*)hreg;
    unsigned int*   embp = (unsigned int*)hreg;                       // 18.0 MB
    unsigned int*   Wp   = (unsigned int*)(hreg + (size_t)Vdim * EPAIR * 4); // 1.2 MB
    unsigned int*   WdP  = (unsigned int*)ws;                         // after lstm

    const size_t lstm_dyn_lds = (size_t)USTAGE * 1024 * 8 * 2;        // 147456 B

    k_pack_u8 <<<dim3(256), dim3(256), 0, stream>>>(Uf, Ub, upk8);
    k_pack_emb<<<dim3((Vdim * EPAIR + 255) / 256), dim3(256), 0, stream>>>(emb, embp);
    k_pack_w  <<<dim3((2 * EPAIR * 1024 + 255) / 256), dim3(256), 0, stream>>>(Wf, Wb, Wp);
    k_xproj   <<<dim3(NROW / 64, 8, 2), dim3(256), 0, stream>>>(tokens, embp, Wp, bf_, bb_, xp);
    k_lstm    <<<dim3(128), dim3(1024), lstm_dyn_lds, stream>>>(upk8, xp, hall);
    k_pack_wd <<<dim3(32), dim3(256), 0, stream>>>(Wd, WdP);
    k_dense   <<<dim3(NROW / 64), dim3(256), 0, stream>>>(hall, WdP, bd, out_logits);
    k_crf     <<<dim3(64), dim3(64), 0, stream>>>(out_logits, targets, lengths, trans, out_ll, out_trans);
}